// Round 21
// baseline (96.601 us; speedup 1.0000x reference)
//
#include <hip/hip_runtime.h>
#include <cstddef>

// ExpFilter via linearity: out = scan_t(X) @ W^T + b*c(t)
//   c(t) = (1 - d^(t+1)) / (1 - d),  d = exp(-1)
// Single-bf16 GEMM: y = bf16(scan(X)) * bf16(W)  (err ~1e-2 << thr 0.0697).
// R21: WAVE-SPECIALIZED pipeline. Block = 512 thr: waves 0-3 = scan
// producers, waves 4-7 = GEMM consumers. 4 chunks x 32 t-rows per block
// (grid 512 = 2 blocks/CU). Stage s: producers scan chunk s (overlaps
// consumers' MFMA+store of chunk s-1); carries chain through a bf16 LDS ring
// (weights d^8, d^16; block warmup = 8 rows on wave 0 only; truncation
// 3.4e-4 << bf16 A-tile quantization 3.9e-3). Two all-wave barriers/stage.
// Scan-state and GEMM-state never coexist in one wave -> no spill pressure
// (the R11/R13/R16 failure). LDS: A dbuf 32K + Y 32K + ring 4K = 68K.
// K0: k_split_w: W -> bf16, pre-tiled panels [kt(8)][kq(4)][row(128)][8].

#define DECAY  0.36787944117144233f
#define D8     3.3546262790251185e-4f  // d^8
#define D16    1.1253517471925912e-7f  // d^16
#define INV1MD 1.5819767068693265f     // 1/(1-d)

typedef __attribute__((ext_vector_type(8))) short short8;
typedef __attribute__((ext_vector_type(4))) short short4v;
typedef __attribute__((ext_vector_type(4))) float f32x4;

static constexpr int T_DIM = 2048, B_DIM = 32, K_DIM = 256, N_DIM = 256;
static constexpr int M_DIM = T_DIM * B_DIM;   // 65536
static constexpr int PS  = 32768;             // shorts per 128-row W panel
static constexpr int CR  = 32;                // t-rows per chunk
static constexpr int NCH = 4;                 // chunks per block (128 rows)

__device__ __forceinline__ float bfbits2f(unsigned short u) {
  unsigned int x = ((unsigned int)u) << 16;
  return __builtin_bit_cast(float, x);
}
__device__ __forceinline__ short f2bf_s(float f) {
  __bf16 h = (__bf16)f;
  return __builtin_bit_cast(short, h);
}

// ---------------- K0: W [O][I] fp32 -> tiled bf16 ----------------
__global__ void k_split_w(const float* __restrict__ W, short* __restrict__ Wh) {
  const int o = blockIdx.x, i = threadIdx.x;
  size_t off = (size_t)(o >> 7) * PS + (i >> 5) * 4096 + ((i >> 3) & 3) * 1024 +
               (o & 127) * 8 + (i & 7);
  Wh[off] = f2bf_s(W[o * 256 + i]);
}

// ---------------- K1: wave-specialized scan||GEMM pipeline ----------------
// grid (T/128=16, B=32) x 512 thr.
__global__ __launch_bounds__(512, 4)
void k_fused(const float* __restrict__ X, const short* __restrict__ Wth,
             const float* __restrict__ bias, float* __restrict__ out) {
  __shared__ __align__(16) char ldsA[32768];   // A-tile double buffer (2x16K)
  __shared__ __align__(16) char ldsY[32768];   // Y bounce (32 rows fp32)
  __shared__ __align__(16) short cring[8 * 256]; // bf16 carry ring (4K)

  const int tid  = threadIdx.x;
  const int lane = tid & 63;
  const int wv   = tid >> 6;
  const int c2   = blockIdx.x;                 // 0..15
  const int b    = blockIdx.y;
  const int t0B  = c2 * (CR * NCH);

  const int ch4   = lane * 4;                  // producer: lane's 4 channels
  const int row16 = lane & 15;
  const int kq    = lane >> 4;
  const bool isP  = (wv < 4);
  const int p     = wv;                        // producer wave id (0..3)

  static constexpr float DP[8] = {             // d^(j+1)
      0.36787944117144233f,  0.1353352832366127f,  0.049787068367863944f,
      0.018315638888734179f, 0.006737946999085467f, 0.0024787521766663585f,
      0.0009118819655545162f, 3.3546262790251185e-4f};

  for (int s = 0; s <= NCH; ++s) {
    f32x4 y[8];
    f32x4 cwarm = {0.f, 0.f, 0.f, 0.f};
    f32x4 acc[2][4] = {};

    // ================= sub-stage 1 =================
    if (isP) {
      if (s < NCH) {
        const int r0 = t0B + s * CR + p * 8;
        const float* xp = X + (size_t)r0 * 8192 + b * 256 + ch4;
        if (s == 0 && p == 0 && c2 > 0) {      // block warmup: 8 rows, wave 0
          const float* wp = xp - (size_t)8 * 8192;
          #pragma unroll
          for (int j = 0; j < 8; ++j) {
            f32x4 xw = *reinterpret_cast<const f32x4*>(wp + (size_t)j * 8192);
            #pragma unroll
            for (int e = 0; e < 4; ++e) cwarm[e] = fmaf(DECAY, cwarm[e], xw[e]);
          }
        }
        #pragma unroll
        for (int j = 0; j < 8; ++j)
          y[j] = *reinterpret_cast<const f32x4*>(xp + (size_t)j * 8192);
        f32x4 sa = {0.f, 0.f, 0.f, 0.f};
        #pragma unroll
        for (int j = 0; j < 8; ++j) {
          #pragma unroll
          for (int e = 0; e < 4; ++e) sa[e] = fmaf(DECAY, sa[e], y[j][e]);
          y[j] = sa;
        }
        short4v cv;                            // publish local carry (bf16)
        #pragma unroll
        for (int e = 0; e < 4; ++e) cv[e] = f2bf_s(y[7][e]);
        *reinterpret_cast<short4v*>(&cring[((4 * s + p) & 7) * 256 + ch4]) = cv;
      }
    } else if (s >= 1) {
      const int c   = s - 1;
      const int cw  = wv - 4;                  // 0..3, owns 64 cols
      const char* A = ldsA + (c & 1) * 16384;
      const short* Wp = Wth + (size_t)(cw >> 1) * PS;
      const int wbase = kq * 1024 + ((cw & 1) * 64 + row16) * 8;

      short8 bh[2][4];
      #pragma unroll
      for (int ct = 0; ct < 4; ++ct)
        bh[0][ct] = *reinterpret_cast<const short8*>(Wp + wbase + ct * 128);
      __builtin_amdgcn_sched_barrier(0);

      #pragma unroll
      for (int kt = 0; kt < 8; ++kt) {
        const int cur = kt & 1;
        if (kt < 7) {
          #pragma unroll
          for (int ct = 0; ct < 4; ++ct)
            bh[cur ^ 1][ct] = *reinterpret_cast<const short8*>(
                Wp + (kt + 1) * 4096 + wbase + ct * 128);
          __builtin_amdgcn_sched_barrier(0);
        }
        short8 ah0, ah1;
        {
          const int b0 = (row16 * 512 + kt * 64 + kq * 16) ^ ((row16 & 7) << 4);
          const int r1 = row16 + 16;
          const int b1 = (r1 * 512 + kt * 64 + kq * 16) ^ ((r1 & 7) << 4);
          ah0 = *reinterpret_cast<const short8*>(A + b0);
          ah1 = *reinterpret_cast<const short8*>(A + b1);
        }
        #pragma unroll
        for (int ct = 0; ct < 4; ++ct) {
          acc[0][ct] = __builtin_amdgcn_mfma_f32_16x16x32_bf16(
              ah0, bh[cur][ct], acc[0][ct], 0, 0, 0);
          acc[1][ct] = __builtin_amdgcn_mfma_f32_16x16x32_bf16(
              ah1, bh[cur][ct], acc[1][ct], 0, 0, 0);
        }
      }
      // acc -> ldsY (C/D: col=lane&15, row=kq*4+j [validated R1-R20])
      #pragma unroll
      for (int rf = 0; rf < 2; ++rf)
        #pragma unroll
        for (int ct = 0; ct < 4; ++ct)
          #pragma unroll
          for (int j = 0; j < 4; ++j) {
            const int rowh = rf * 16 + kq * 4 + j;
            const int col  = cw * 64 + ct * 16 + row16;
            const int byte = (rowh * 1024 + col * 4) ^ ((rowh & 7) << 4);
            *reinterpret_cast<float*>(ldsY + byte) = acc[rf][ct][j];
          }
    }
    __syncthreads();                           // B_mid

    // ================= sub-stage 2 =================
    if (isP) {
      if (s < NCH) {
        f32x4 cin = cwarm;                     // ring combine: d^0, d^8, d^16
        {
          const int g1 = 4 * s + p - 1;
          if (g1 >= 0) {
            short4v cv = *reinterpret_cast<const short4v*>(
                &cring[(g1 & 7) * 256 + ch4]);
            #pragma unroll
            for (int e = 0; e < 4; ++e)
              cin[e] += bfbits2f((unsigned short)cv[e]);
          }
          if (g1 >= 1) {
            short4v cv = *reinterpret_cast<const short4v*>(
                &cring[((g1 - 1) & 7) * 256 + ch4]);
            #pragma unroll
            for (int e = 0; e < 4; ++e)
              cin[e] = fmaf(bfbits2f((unsigned short)cv[e]), D8, cin[e]);
          }
          if (g1 >= 2) {
            short4v cv = *reinterpret_cast<const short4v*>(
                &cring[((g1 - 2) & 7) * 256 + ch4]);
            #pragma unroll
            for (int e = 0; e < 4; ++e)
              cin[e] = fmaf(bfbits2f((unsigned short)cv[e]), D16, cin[e]);
          }
        }
        char* A = ldsA + (s & 1) * 16384;      // fixup + write A-tile
        #pragma unroll
        for (int j = 0; j < 8; ++j) {
          const int row = p * 8 + j;
          short4v hv;
          #pragma unroll
          for (int e = 0; e < 4; ++e)
            hv[e] = f2bf_s(fmaf(cin[e], DP[j], y[j][e]));
          const int byte = (row * 512 + ch4 * 2) ^ ((row & 7) << 4);
          *reinterpret_cast<short4v*>(A + byte) = hv;
        }
      }
    } else if (s >= 1) {
      const int t0c  = t0B + (s - 1) * CR;
      const int ctid = tid - 256;              // 0..255
      const f32x4* bias4 = reinterpret_cast<const f32x4*>(bias);
      #pragma unroll
      for (int q = 0; q < 8; ++q) {
        const int idx  = ctid + q * 256;       // 0..2047
        const int rowh = idx >> 6;             // 0..31
        const int colc = idx & 63;
        const int byte = (idx * 16) ^ ((rowh & 7) << 4);
        f32x4 yv = *reinterpret_cast<const f32x4*>(ldsY + byte);
        f32x4 bv = bias4[colc];
        const float cf =
            (1.f - __expf(-(float)(t0c + rowh + 1))) * INV1MD;
        f32x4 r;
        #pragma unroll
        for (int e = 0; e < 4; ++e) r[e] = fmaf(bv[e], cf, yv[e]);
        __builtin_nontemporal_store(
            r, reinterpret_cast<f32x4*>(
                   out + ((size_t)(t0c + rowh) * 32 + b) * 256 + colc * 4));
      }
    }
    __syncthreads();                           // B_end
  }
}

// ---------------- fallback (ws too small): naive fp32 ----------------
__global__ void k_fb_gemm(const float* __restrict__ X, const float* __restrict__ W,
                          const float* __restrict__ bias, float* __restrict__ Y) {
  size_t idx = (size_t)blockIdx.x * 256 + threadIdx.x;
  int o = (int)(idx & 255);
  size_t m = idx >> 8;
  const float* x = X + m * 256;
  const float* w = W + (size_t)o * 256;
  float s = bias[o];
  for (int k = 0; k < 256; ++k) s = fmaf(x[k], w[k], s);
  Y[idx] = s;
}
__global__ void k_fb_scan(float* __restrict__ Y) {
  int ch = blockIdx.x * 256 + threadIdx.x;
  float s = 0.f;
  float* p = Y + ch;
  for (int t = 0; t < 2048; ++t) { s = fmaf(DECAY, s, *p); *p = s; p += 8192; }
}

extern "C" void kernel_launch(void* const* d_in, const int* in_sizes, int n_in,
                              void* d_out, int out_size, void* d_ws, size_t ws_size,
                              hipStream_t stream) {
  const float* X    = (const float*)d_in[0];
  const float* W    = (const float*)d_in[1];
  const float* bias = (const float*)d_in[2];
  float* out = (float*)d_out;

  const size_t w_elems = (size_t)N_DIM * K_DIM;                 // 65536
  const size_t need    = w_elems * sizeof(short);               // 128 KiB

  if (ws_size >= need) {
    short* Wh = (short*)d_ws;
    k_split_w<<<N_DIM, 256, 0, stream>>>(W, Wh);
    k_fused<<<dim3(T_DIM / (CR * NCH), B_DIM), 512, 0, stream>>>(X, Wh, bias,
                                                                 out);
  } else {
    k_fb_gemm<<<M_DIM, 256, 0, stream>>>(X, W, bias, out);
    k_fb_scan<<<32, 256, 0, stream>>>(out);
  }
}

// Round 22
// 33.642 us; speedup vs baseline: 2.8715x; 2.8715x over previous
//
#include <hip/hip_runtime.h>
#include <cstddef>

// ExpFilter via linearity: out = scan_t(X) @ W^T + b*c(t)
//   c(t) = (1 - d^(t+1)) / (1 - d),  d = exp(-1)
// Single-bf16 GEMM: y = bf16(scan(X)) * bf16(W)  (err ~1e-2 << thr 0.0697).
// == FINAL: exact R18/R20 kernel (best measured: 34.27 / 34.33 us). ==
// Failed branches (all reverted): register cross-chunk pipelining (R11/R13/
// R16: spill), TCH=32 TLP (R19: occupancy did not rise), wave specialization
// (R21: y[] live across barrier + path-union -> 76 MB scratch, 96 us).
// K0: k_split_w: W -> bf16, pre-tiled panels [kt(8)][kq(4)][row(128)][8].
// K1: k_fused, 512 thr = 8 waves, block = (64 t-rows, one b):
//   Phase A (balanced carry-scan): wave w owns 9 rows [w*9-8, w*9], lane owns
//     4 channels; in-place scan in y[9]; bf16 carries (4KB LDS), weight d^9;
//     fixup y += cin*d^(j+1); bf16 A-tile (32KB) XOR-swizzled.
//   Phase B: 8 waves x (64r x 32c); W 1-kt triple-buffer (distance 2,
//     sched_barrier-pinned issue), ah 2-at-a-time. 64 MFMA.
//   Epilogue: two 32-row half-passes through LDS -> coalesced f32x4
//     NON-TEMPORAL stores (out never re-read; protect X/W cache residency).

#define DECAY  0.36787944117144233f
#define D9     1.2340980408667956e-4f  // d^9
#define INV1MD 1.5819767068693265f     // 1/(1-d)

typedef __attribute__((ext_vector_type(8))) short short8;
typedef __attribute__((ext_vector_type(4))) short short4v;
typedef __attribute__((ext_vector_type(4))) float f32x4;

static constexpr int T_DIM = 2048, B_DIM = 32, K_DIM = 256, N_DIM = 256;
static constexpr int M_DIM = T_DIM * B_DIM;   // 65536
static constexpr int PS  = 32768;             // shorts per 128-row W panel
static constexpr int TCH = 64;                // t-rows per block

__device__ __forceinline__ float bfbits2f(unsigned short u) {
  unsigned int x = ((unsigned int)u) << 16;
  return __builtin_bit_cast(float, x);
}
__device__ __forceinline__ short f2bf_s(float f) {
  __bf16 h = (__bf16)f;
  return __builtin_bit_cast(short, h);
}

// ---------------- K0: W [O][I] fp32 -> tiled bf16 ----------------
__global__ void k_split_w(const float* __restrict__ W, short* __restrict__ Wh) {
  const int o = blockIdx.x, i = threadIdx.x;
  size_t off = (size_t)(o >> 7) * PS + (i >> 5) * 4096 + ((i >> 3) & 3) * 1024 +
               (o & 127) * 8 + (i & 7);
  Wh[off] = f2bf_s(W[o * 256 + i]);
}

// ---------------- K1: fused balanced carry-scan + GEMM ----------------
// grid (T/64=32, B=32) x 512 thr = 8 waves.
__global__ __launch_bounds__(512, 6)
void k_fused(const float* __restrict__ X, const short* __restrict__ Wth,
             const float* __restrict__ bias, float* __restrict__ out) {
  __shared__ __align__(16) char ldsA[32768];   // bf16 A-tile; later Y half
  __shared__ __align__(16) short cbh[8 * 256]; // bf16 carries (4 KB)
  __shared__ float cfac[TCH];

  const int tid  = threadIdx.x;
  const int lane = tid & 63;
  const int wv   = tid >> 6;
  const int c    = blockIdx.x;
  const int b    = blockIdx.y;
  const int t0   = c * TCH;
  const int ch4  = lane * 4;                   // lane's 4 channels

  const int row16 = lane & 15;
  const int kq    = lane >> 4;
  const int cg    = wv;                        // col group: 32 cols
  const short* Wp = Wth + (size_t)(cg >> 2) * PS;
  const int wbase = kq * 1024 + ((cg & 3) * 32 + row16) * 8;  // +kt*4096+ct*128

  if (tid < TCH)
    cfac[tid] = (1.f - __expf(-(float)(t0 + tid + 1))) * INV1MD;

  // ---- Phase A: wave w scans rows r = w*9+j-8 (j=0..8); in-place in y ----
  f32x4 y[9];
  {
    const int ts = t0 + wv * 9 - 8;
    if (ts >= 0) {                             // all waves except (c==0,wv==0)
      const float* xp = X + (size_t)ts * 8192 + b * 256 + ch4;
      #pragma unroll
      for (int j = 0; j < 9; ++j)
        y[j] = *reinterpret_cast<const f32x4*>(xp + (size_t)j * 8192);
      f32x4 s = {0.f, 0.f, 0.f, 0.f};
      #pragma unroll
      for (int j = 0; j < 9; ++j) {
        #pragma unroll
        for (int e = 0; e < 4; ++e) s[e] = fmaf(DECAY, s[e], y[j][e]);
        y[j] = s;
      }
    } else {                                   // c==0, wv==0: only t=0 exists
      y[8] = *reinterpret_cast<const f32x4*>(X + b * 256 + ch4);
    }
  }
  {                                            // publish local carry (bf16)
    short4v cv;
    #pragma unroll
    for (int e = 0; e < 4; ++e) cv[e] = f2bf_s(y[8][e]);
    *reinterpret_cast<short4v*>(&cbh[wv * 256 + ch4]) = cv;
  }

  // ---- issue W kt=0 now: latency hides under barrier + cin + fixup ----
  short8 bh[3][2];                             // triple buffer, distance 2
  #pragma unroll
  for (int ct = 0; ct < 2; ++ct)
    bh[0][ct] = *reinterpret_cast<const short8*>(Wp + wbase + ct * 128);
  __builtin_amdgcn_sched_barrier(0);

  __syncthreads();                             // carries + cfac visible

  // cin = global state before this wave's rows = sum_{u<wv} c_u d^(9(wv-1-u))
  f32x4 cin = {0.f, 0.f, 0.f, 0.f};
  {
    float m = 1.f;
    for (int v = wv - 1; v >= 0; --v) {
      short4v cv = *reinterpret_cast<const short4v*>(&cbh[v * 256 + ch4]);
      #pragma unroll
      for (int e = 0; e < 4; ++e)
        cin[e] = fmaf(bfbits2f((unsigned short)cv[e]), m, cin[e]);
      m *= D9;
    }
  }

  // fixup + convert + write A-tile (row stride 512B, byte ^= (row&7)<<4)
  {
    static constexpr float DP[9] = {
        0.36787944117144233f, 0.1353352832366127f,  0.049787068367863944f,
        0.018315638888734179f, 0.006737946999085467f, 0.0024787521766663585f,
        0.0009118819655545162f, 0.00033546262790251185f, 1.2340980408667956e-4f};
    #pragma unroll
    for (int j = 0; j < 9; ++j) {
      const int r = wv * 9 + j - 8;
      if (r >= 0) {                            // wave-uniform per j
        short4v hv;
        #pragma unroll
        for (int e = 0; e < 4; ++e)
          hv[e] = f2bf_s(fmaf(cin[e], DP[j], y[j][e]));
        const int byte = (r * 512 + ch4 * 2) ^ ((r & 7) << 4);
        *reinterpret_cast<short4v*>(ldsA + byte) = hv;
      }
    }
  }
  __syncthreads();                             // A-tile ready

  // ---- issue W kt=1 (second pipeline stage) ----
  #pragma unroll
  for (int ct = 0; ct < 2; ++ct)
    bh[1][ct] = *reinterpret_cast<const short8*>(Wp + 4096 + wbase + ct * 128);
  __builtin_amdgcn_sched_barrier(0);

  // ---- Phase B: 64 MFMA, W triple-buffer (distance 2), ah 2-at-a-time ----
  f32x4 acc[4][2] = {};
  #pragma unroll
  for (int kt = 0; kt < 8; ++kt) {
    const int cur = kt % 3;
    if (kt < 6) {                              // issue kt+2 into (kt+2)%3
      #pragma unroll
      for (int ct = 0; ct < 2; ++ct)
        bh[(kt + 2) % 3][ct] = *reinterpret_cast<const short8*>(
            Wp + (kt + 2) * 4096 + wbase + ct * 128);
      __builtin_amdgcn_sched_barrier(0);       // pin issue before kt's MFMAs
    }
    #pragma unroll
    for (int rh = 0; rh < 2; ++rh) {
      short8 ah0, ah1;
      {
        const int row0 = rh * 32 + row16;
        const int b0 = (row0 * 512 + kt * 64 + kq * 16) ^ ((row0 & 7) << 4);
        const int row1 = row0 + 16;
        const int b1 = (row1 * 512 + kt * 64 + kq * 16) ^ ((row1 & 7) << 4);
        ah0 = *reinterpret_cast<const short8*>(ldsA + b0);
        ah1 = *reinterpret_cast<const short8*>(ldsA + b1);
      }
      #pragma unroll
      for (int ct = 0; ct < 2; ++ct) {
        acc[rh * 2][ct] = __builtin_amdgcn_mfma_f32_16x16x32_bf16(
            ah0, bh[cur][ct], acc[rh * 2][ct], 0, 0, 0);
        acc[rh * 2 + 1][ct] = __builtin_amdgcn_mfma_f32_16x16x32_bf16(
            ah1, bh[cur][ct], acc[rh * 2 + 1][ct], 0, 0, 0);
      }
    }
  }

  // ---- Epilogue: two 32-row half-passes through ldsA (32 KB) ----
  // C/D layout: col = lane&15, row = kq*4 + j  [validated R1-R20]
  const f32x4* bias4 = reinterpret_cast<const f32x4*>(bias);
  #pragma unroll
  for (int p = 0; p < 2; ++p) {
    __syncthreads();       // p0: A-tile reads done; p1: pass-0 LDS reads done
    #pragma unroll
    for (int rt = 2 * p; rt < 2 * p + 2; ++rt)
      #pragma unroll
      for (int ct = 0; ct < 2; ++ct)
        #pragma unroll
        for (int j = 0; j < 4; ++j) {
          const int rowh = (rt * 16 + kq * 4 + j) & 31;
          const int col  = cg * 32 + ct * 16 + row16;
          const int byte = (rowh * 1024 + col * 4) ^ ((rowh & 7) << 4);
          *reinterpret_cast<float*>(ldsA + byte) = acc[rt][ct][j];
        }
    __syncthreads();
    #pragma unroll
    for (int q = 0; q < 4; ++q) {
      const int idx  = tid + q * 512;          // 0..2047
      const int rowh = idx >> 6;
      const int colc = idx & 63;
      const int byte = (idx * 16) ^ ((rowh & 7) << 4);
      f32x4 yv = *reinterpret_cast<const f32x4*>(ldsA + byte);
      const int row = p * 32 + rowh;
      f32x4 bv = bias4[colc];
      const float cf = cfac[row];
      f32x4 r;
      #pragma unroll
      for (int e = 0; e < 4; ++e) r[e] = fmaf(bv[e], cf, yv[e]);
      __builtin_nontemporal_store(
          r, reinterpret_cast<f32x4*>(out + ((size_t)(t0 + row) * 32 + b) * 256 +
                                      colc * 4));
    }
  }
}

// ---------------- fallback (ws too small): naive fp32 ----------------
__global__ void k_fb_gemm(const float* __restrict__ X, const float* __restrict__ W,
                          const float* __restrict__ bias, float* __restrict__ Y) {
  size_t idx = (size_t)blockIdx.x * 256 + threadIdx.x;
  int o = (int)(idx & 255);
  size_t m = idx >> 8;
  const float* x = X + m * 256;
  const float* w = W + (size_t)o * 256;
  float s = bias[o];
  for (int k = 0; k < 256; ++k) s = fmaf(x[k], w[k], s);
  Y[idx] = s;
}
__global__ void k_fb_scan(float* __restrict__ Y) {
  int ch = blockIdx.x * 256 + threadIdx.x;
  float s = 0.f;
  float* p = Y + ch;
  for (int t = 0; t < 2048; ++t) { s = fmaf(DECAY, s, *p); *p = s; p += 8192; }
}

extern "C" void kernel_launch(void* const* d_in, const int* in_sizes, int n_in,
                              void* d_out, int out_size, void* d_ws, size_t ws_size,
                              hipStream_t stream) {
  const float* X    = (const float*)d_in[0];
  const float* W    = (const float*)d_in[1];
  const float* bias = (const float*)d_in[2];
  float* out = (float*)d_out;

  const size_t w_elems = (size_t)N_DIM * K_DIM;                 // 65536
  const size_t need    = w_elems * sizeof(short);               // 128 KiB

  if (ws_size >= need) {
    short* Wh = (short*)d_ws;
    k_split_w<<<N_DIM, 256, 0, stream>>>(W, Wh);
    k_fused<<<dim3(T_DIM / TCH, B_DIM), 512, 0, stream>>>(X, Wh, bias, out);
  } else {
    k_fb_gemm<<<M_DIM, 256, 0, stream>>>(X, W, bias, out);
    k_fb_scan<<<32, 256, 0, stream>>>(out);
  }
}